// Round 11
// baseline (82.873 us; speedup 1.0000x reference)
//
#include <hip/hip_runtime.h>
#include <hip/hip_bf16.h>
#include <math.h>

#define B_  128
#define N_  16
#define T_  200
#define H_  64
#define J1  80
#define J2  40
#define NTILE 13
#define NEGV -4294967295.0f   // -2^32 + 1

typedef __attribute__((ext_vector_type(8))) short bf16x8;
typedef __attribute__((ext_vector_type(4))) float f32x4;

__device__ __forceinline__ float sigmoidf_(float x) {
    return 1.0f / (1.0f + __expf(-x));
}
// branch-free RNE f32->bf16 (finite inputs only)
__device__ __forceinline__ short f2b(float x) {
    unsigned u = __float_as_uint(x);
    return (short)((u + 0x7FFF + ((u >> 16) & 1)) >> 16);
}
__device__ __forceinline__ float b2f(short s) {
    unsigned u = ((unsigned)(unsigned short)s) << 16;
    return __uint_as_float(u);
}
__device__ __forceinline__ unsigned pack2(float a, float b) {
    return (unsigned)(unsigned short)f2b(a) | ((unsigned)(unsigned short)f2b(b) << 16);
}

// ---- prep: ONE dispatch, 4 ranges --------------------------------------
// [0,160):    QW[bn][j] = b1[j] + sum_h q*(W1a+W1c)      (2048*20 thr, exact)
// [160,180):  WBF = [W1d ; W1b-W1c] frag-ordered bf16     (5120 thr, exact)
// [180,596):  keys -> frag-ordered bf16 A-frags           (106496 thr, exact;
//             R7-R10 under-launched this 4x — fixed to 416 blocks)
// [596,605):  W2 -> frag-ordered bf16 (k pad 96, m pad 48)(2304 thr)
#define P_QW 160
#define P_WB 20
#define P_KB 416
#define P_W2 9
__global__ void prep(const float* __restrict__ queries,
                     const float* __restrict__ keys,
                     const float* __restrict__ W1,
                     const float* __restrict__ b1,
                     const float* __restrict__ W2,
                     float* __restrict__ QW,
                     unsigned* __restrict__ WBFu,
                     bf16x8* __restrict__ kbf0, bf16x8* __restrict__ kbf1,
                     unsigned* __restrict__ W2F) {
    const int blk = blockIdx.x, tid = threadIdx.x;
    if (blk < P_QW) {
        int idx = blk * 256 + tid;                 // (bn, j/4)
        int bn = idx / 20, j = (idx % 20) * 4;
        float4 acc = *(const float4*)(b1 + j);
        const float* qp = queries + bn * H_;
        for (int h = 0; h < H_; ++h) {
            float qh = qp[h];
            float4 wa = *(const float4*)(W1 + h * J1 + j);
            float4 wc = *(const float4*)(W1 + (128 + h) * J1 + j);
            acc.x = fmaf(qh, wa.x + wc.x, acc.x);
            acc.y = fmaf(qh, wa.y + wc.y, acc.y);
            acc.z = fmaf(qh, wa.z + wc.z, acc.z);
            acc.w = fmaf(qh, wa.w + wc.w, acc.w);
        }
        *(float4*)(QW + bn * J1 + j) = acc;
    } else if (blk < P_QW + P_WB) {
        // WBF frag fi = s*5+nt (s<4 k-slice, nt<5 col-tile); lane l holds
        // rows R = s*32 + 8*(l>>4) + 2rp (+1), col j = nt*16 + (l&15).
        // Rows 0..63 = W1d, rows 64..127 = W1b - W1c.
        int idx = (blk - P_QW) * 256 + tid;        // = fi*256 + l*4 + rp, exact
        int rp = idx & 3, l = (idx >> 2) & 63, fi = idx >> 8;
        int j  = (fi % 5) * 16 + (l & 15);
        int R  = (fi / 5) * 32 + 8 * (l >> 4) + 2 * rp;
        float a, b;
        if (R < 64) {
            a = W1[(192 + R) * J1 + j];
            b = W1[(193 + R) * J1 + j];
        } else {
            int r2 = R - 64;
            a = W1[(64 + r2) * J1 + j] - W1[(128 + r2) * J1 + j];
            b = W1[(65 + r2) * J1 + j] - W1[(129 + r2) * J1 + j];
        }
        WBFu[idx] = pack2(a, b);
    } else if (blk < P_QW + P_WB + P_KB) {
        int idx = (blk - P_QW - P_WB) * 256 + tid; // (b*13+mt)*64+l, exact
        int l  = idx & 63, bm = idx >> 6;
        int mt = bm % NTILE, b = bm / NTILE;
        int t  = mt * 16 + (l & 15); if (t > T_ - 1) t = T_ - 1;
        int rg = l >> 4;
        const float* kr = keys + ((size_t)(b * T_ + t)) * H_ + 8 * rg;
        float4 a0 = *(const float4*)(kr);
        float4 a1 = *(const float4*)(kr + 4);
        float4 a2 = *(const float4*)(kr + 32);
        float4 a3 = *(const float4*)(kr + 36);
        bf16x8 f0, f1;
        f0[0] = f2b(a0.x); f0[1] = f2b(a0.y); f0[2] = f2b(a0.z); f0[3] = f2b(a0.w);
        f0[4] = f2b(a1.x); f0[5] = f2b(a1.y); f0[6] = f2b(a1.z); f0[7] = f2b(a1.w);
        f1[0] = f2b(a2.x); f1[1] = f2b(a2.y); f1[2] = f2b(a2.z); f1[3] = f2b(a2.w);
        f1[4] = f2b(a3.x); f1[5] = f2b(a3.y); f1[6] = f2b(a3.z); f1[7] = f2b(a3.w);
        kbf0[idx] = f0; kbf1[idx] = f1;
    } else {
        int idx = (blk - P_QW - P_WB - P_KB) * 256 + tid;
        if (idx < 9 * 64 * 4) {
            int rp = idx & 3;
            int l  = (idx >> 2) & 63;
            int f  = idx >> 8;
            int m  = (f / 3) * 16 + (l & 15);
            int k0 = (f % 3) * 32 + 8 * (l >> 4) + 2 * rp;
            float a = (k0     < J1 && m < J2) ? W2[k0 * J2 + m]       : 0.0f;
            float b = (k0 + 1 < J1 && m < J2) ? W2[(k0 + 1) * J2 + m] : 0.0f;
            W2F[idx] = pack2(a, b);
        }
    }
}

// ---- fused main: block per bn, 13 WAVES (one tile each) -----------------
// Z1 = [Kq | K] @ [W1d ; wbc] + QW: the B operand WBF is FIXED (20 KB,
// L1-resident for every wave) -- no per-bn Bnf buffer, no prep2 dispatch.
// Per-block serial chain = ONE tile pass, then softmax + 13-way PV.
__global__ __launch_bounds__(832) void attn13(
        const float* __restrict__ queries, const float* __restrict__ keys,
        const int*   __restrict__ keys_length,
        const float* __restrict__ QW,
        const bf16x8* __restrict__ kbf0, const bf16x8* __restrict__ kbf1,
        const bf16x8* __restrict__ WBF, const bf16x8* __restrict__ W2F,
        const float* __restrict__ b2, const float* __restrict__ W3,
        const float* __restrict__ b3,
        float* __restrict__ out) {
    const int tid  = threadIdx.x;
    const int lane = tid & 63, wv = tid >> 6;            // 13 waves
    const int bn   = (blockIdx.x & 7) * 256 + (blockIdx.x >> 3);  // XCD swizzle
    const int b    = bn >> 4;
    const int cl   = lane & 15, rg = lane >> 4;
    const int mt   = wv;                                 // wave = tile

    __shared__ __align__(16) short X1[NTILE][16][104];   // 43,264 B
    __shared__ float z3s[NTILE * 16];
    __shared__ float wsm[T_];
    __shared__ float part[NTILE * 64];
    __shared__ float red[32];

    // zero own-slice k-pad cols 80..95 (wave-local, in-order LDS)
    #pragma unroll
    for (int i = 0; i < 4; ++i)
        X1[wv][rg + 4 * i][80 + cl] = 0;

    // A-frags: K (bf16, precomputed) and Kq = K * q (in-register)
    bf16x8 k0 = kbf0[(b * NTILE + mt) * 64 + lane];
    bf16x8 k1 = kbf1[(b * NTILE + mt) * 64 + lane];
    const float* qp = queries + bn * H_;
    float4 qa = *(const float4*)(qp + 8 * rg);
    float4 qb = *(const float4*)(qp + 8 * rg + 4);
    float4 qc = *(const float4*)(qp + 32 + 8 * rg);
    float4 qd = *(const float4*)(qp + 36 + 8 * rg);
    bf16x8 kq0, kq1;
    kq0[0] = f2b(b2f(k0[0]) * qa.x); kq0[1] = f2b(b2f(k0[1]) * qa.y);
    kq0[2] = f2b(b2f(k0[2]) * qa.z); kq0[3] = f2b(b2f(k0[3]) * qa.w);
    kq0[4] = f2b(b2f(k0[4]) * qb.x); kq0[5] = f2b(b2f(k0[5]) * qb.y);
    kq0[6] = f2b(b2f(k0[6]) * qb.z); kq0[7] = f2b(b2f(k0[7]) * qb.w);
    kq1[0] = f2b(b2f(k1[0]) * qc.x); kq1[1] = f2b(b2f(k1[1]) * qc.y);
    kq1[2] = f2b(b2f(k1[2]) * qc.z); kq1[3] = f2b(b2f(k1[3]) * qc.w);
    kq1[4] = f2b(b2f(k1[4]) * qd.x); kq1[5] = f2b(b2f(k1[5]) * qd.y);
    kq1[6] = f2b(b2f(k1[6]) * qd.z); kq1[7] = f2b(b2f(k1[7]) * qd.w);

    // layer 1: Z1 = [Kq|K] @ WBF + QW  (WBF L1-hot: shared by all waves)
    f32x4 acc[5];
    #pragma unroll
    for (int nt = 0; nt < 5; ++nt) {
        float qv = QW[bn * J1 + cl + 16 * nt];
        acc[nt][0] = qv; acc[nt][1] = qv; acc[nt][2] = qv; acc[nt][3] = qv;
    }
    #pragma unroll
    for (int nt = 0; nt < 5; ++nt) {
        acc[nt] = __builtin_amdgcn_mfma_f32_16x16x32_bf16(kq0, WBF[( 0 + nt) * 64 + lane], acc[nt], 0, 0, 0);
        acc[nt] = __builtin_amdgcn_mfma_f32_16x16x32_bf16(kq1, WBF[( 5 + nt) * 64 + lane], acc[nt], 0, 0, 0);
        acc[nt] = __builtin_amdgcn_mfma_f32_16x16x32_bf16(k0,  WBF[(10 + nt) * 64 + lane], acc[nt], 0, 0, 0);
        acc[nt] = __builtin_amdgcn_mfma_f32_16x16x32_bf16(k1,  WBF[(15 + nt) * 64 + lane], acc[nt], 0, 0, 0);
    }

    // sigmoid -> X1 own slice (C layout: row = rg*4+i, col = cl+16nt)
    #pragma unroll
    for (int nt = 0; nt < 5; ++nt)
        #pragma unroll
        for (int i = 0; i < 4; ++i)
            X1[wv][rg * 4 + i][cl + 16 * nt] = f2b(sigmoidf_(acc[nt][i]));

    // layer 2: Z2 = X1 @ W2 + b2
    float b2v[3], w3v[3];
    #pragma unroll
    for (int nt = 0; nt < 3; ++nt) {
        int m  = cl + 16 * nt;
        int mc = m < J2 ? m : J2 - 1;
        b2v[nt] = b2[mc];
        w3v[nt] = (m < J2) ? W3[mc] : 0.0f;
    }
    const float b3v = b3[0];
    f32x4 acc2[3];
    #pragma unroll
    for (int nt = 0; nt < 3; ++nt) {
        float bv = b2v[nt];
        acc2[nt][0] = bv; acc2[nt][1] = bv; acc2[nt][2] = bv; acc2[nt][3] = bv;
    }
    #pragma unroll
    for (int ks = 0; ks < 3; ++ks) {
        bf16x8 a2 = *(const bf16x8*)&X1[wv][cl][8 * rg + 32 * ks];
        acc2[0] = __builtin_amdgcn_mfma_f32_16x16x32_bf16(a2, W2F[(0 + ks) * 64 + lane], acc2[0], 0, 0, 0);
        acc2[1] = __builtin_amdgcn_mfma_f32_16x16x32_bf16(a2, W2F[(3 + ks) * 64 + lane], acc2[1], 0, 0, 0);
        acc2[2] = __builtin_amdgcn_mfma_f32_16x16x32_bf16(a2, W2F[(6 + ks) * 64 + lane], acc2[2], 0, 0, 0);
    }

    // layer 3 + 16-lane reduce -> z3s
    float p0 = 0.f, p1 = 0.f, p2 = 0.f, p3 = 0.f;
    #pragma unroll
    for (int nt = 0; nt < 3; ++nt) {
        p0 = fmaf(sigmoidf_(acc2[nt][0]), w3v[nt], p0);
        p1 = fmaf(sigmoidf_(acc2[nt][1]), w3v[nt], p1);
        p2 = fmaf(sigmoidf_(acc2[nt][2]), w3v[nt], p2);
        p3 = fmaf(sigmoidf_(acc2[nt][3]), w3v[nt], p3);
    }
    #pragma unroll
    for (int off = 1; off < 16; off <<= 1) {
        p0 += __shfl_xor(p0, off);
        p1 += __shfl_xor(p1, off);
        p2 += __shfl_xor(p2, off);
        p3 += __shfl_xor(p3, off);
    }
    if (cl == 0) {
        z3s[mt * 16 + rg * 4 + 0] = p0 + b3v;
        z3s[mt * 16 + rg * 4 + 1] = p1 + b3v;
        z3s[mt * 16 + rg * 4 + 2] = p2 + b3v;
        z3s[mt * 16 + rg * 4 + 3] = p3 + b3v;
    }
    __syncthreads();

    // ---- mask + scale + softmax (13-wave reduction; t = tid < 200) ----
    const int L = keys_length[b];
    float s = (tid < T_) ? ((tid < L) ? z3s[tid] : NEGV) * 0.125f : -3.0e38f;

    float mx = s;
    #pragma unroll
    for (int off = 32; off > 0; off >>= 1) mx = fmaxf(mx, __shfl_xor(mx, off));
    if (lane == 0) red[wv] = mx;
    __syncthreads();
    mx = red[0];
    #pragma unroll
    for (int w = 1; w < NTILE; ++w) mx = fmaxf(mx, red[w]);

    float e = (tid < T_) ? __expf(s - mx) : 0.0f;
    float sm = e;
    #pragma unroll
    for (int off = 32; off > 0; off >>= 1) sm += __shfl_xor(sm, off);
    __syncthreads();                                  // red[0..12] consumed
    if (lane == 0) red[16 + wv] = sm;
    __syncthreads();
    sm = red[16];
    #pragma unroll
    for (int w = 1; w < NTILE; ++w) sm += red[16 + w];

    if (tid < T_) wsm[tid] = e / sm;
    __syncthreads();

    // ---- PV: wave w covers t in [16w, min(16w+16,200)); h = lane ----
    const float* kb = keys + (size_t)b * T_ * H_;
    {
        int tb = wv * 16;
        int te = tb + 16 < T_ ? tb + 16 : T_;
        float acc_ = 0.f;
        for (int t = tb; t < te; ++t)
            acc_ = fmaf(wsm[t], kb[(size_t)t * H_ + lane], acc_);
        part[wv * 64 + lane] = acc_;
    }
    __syncthreads();
    if (tid < 64) {
        float o = 0.f;
        #pragma unroll
        for (int w = 0; w < NTILE; ++w) o += part[w * 64 + tid];
        out[bn * H_ + tid] = o;
    }
}

// --- fallback (no workspace): round-3 verified pure-VALU kernel ----------
__global__ __launch_bounds__(256, 3) void attn_nows(
        const float* __restrict__ queries, const float* __restrict__ keys,
        const int*   __restrict__ keys_length,
        const float* __restrict__ W1, const float* __restrict__ b1,
        const float* __restrict__ W2, const float* __restrict__ b2,
        const float* __restrict__ W3, const float* __restrict__ b3,
        float* __restrict__ out) {
    const int tid = threadIdx.x;
    const int bn = (blockIdx.x & 7) * 256 + (blockIdx.x >> 3);
    const int b  = bn >> 4;

    __shared__ float kT[H_][T_ + 1];
    __shared__ float wsm[T_];
    __shared__ float part[256];
    __shared__ float red[8];
    __shared__ float QWq[J1];

    for (int idx = tid; idx < T_ * H_; idx += 256) {
        int t = idx >> 6, h = idx & 63;
        kT[h][t] = keys[(b * T_ + t) * H_ + h];
    }
    if (tid < J1) {
        float acc = b1[tid];
        const float* qp = queries + bn * H_;
        for (int h = 0; h < H_; ++h)
            acc = fmaf(qp[h], W1[h * J1 + tid] + W1[(128 + h) * J1 + tid], acc);
        QWq[tid] = acc;
    }
    __syncthreads();

    const int tt = (tid < T_) ? tid : 0;
    const float* qp = queries + bn * H_;

    float qk[H_];
    #pragma unroll
    for (int h = 0; h < H_; ++h) qk[h] = qp[h] * kT[h][tt];

    float z2[J2];
    #pragma unroll
    for (int m = 0; m < J2; ++m) z2[m] = b2[m];

    #pragma unroll 1
    for (int c = 0; c < 4; ++c) {
        const int j0 = c * 20;
        float z1c[20];
        #pragma unroll
        for (int j = 0; j < 20; ++j) z1c[j] = QWq[j0 + j];
        #pragma unroll
        for (int h = 0; h < H_; ++h) {
            float kh = kT[h][tt];
            const float* Wd = W1 + (192 + h) * J1 + j0;
            const float* Wb = W1 + (64 + h) * J1 + j0;
            const float* Wc = W1 + (128 + h) * J1 + j0;
            #pragma unroll
            for (int j = 0; j < 20; ++j)
                z1c[j] = fmaf(qk[h], Wd[j], fmaf(kh, Wb[j] - Wc[j], z1c[j]));
        }
        #pragma unroll
        for (int j = 0; j < 20; ++j) {
            float x = sigmoidf_(z1c[j]);
            const float* w2 = W2 + (j0 + j) * J2;
            #pragma unroll
            for (int m = 0; m < J2; ++m) z2[m] = fmaf(x, w2[m], z2[m]);
        }
    }

    float z3 = b3[0];
    #pragma unroll
    for (int m = 0; m < J2; ++m) z3 = fmaf(sigmoidf_(z2[m]), W3[m], z3);

    const int L = keys_length[b];
    float s = (tid < T_) ? ((tid < L) ? z3 : NEGV) * 0.125f : -3.0e38f;

    float mx = s;
    #pragma unroll
    for (int off = 32; off > 0; off >>= 1) mx = fmaxf(mx, __shfl_xor(mx, off));
    if ((tid & 63) == 0) red[tid >> 6] = mx;
    __syncthreads();
    mx = fmaxf(fmaxf(red[0], red[1]), fmaxf(red[2], red[3]));

    float e = (tid < T_) ? __expf(s - mx) : 0.0f;
    float sm = e;
    #pragma unroll
    for (int off = 32; off > 0; off >>= 1) sm += __shfl_xor(sm, off);
    __syncthreads();
    if ((tid & 63) == 0) red[4 + (tid >> 6)] = sm;
    __syncthreads();
    sm = red[4] + red[5] + red[6] + red[7];

    if (tid < T_) wsm[tid] = e / sm;
    __syncthreads();

    {
        int h = tid & 63, p = tid >> 6;
        float acc = 0.f;
        int t0 = p * 50;
        for (int t = t0; t < t0 + 50; ++t)
            acc = fmaf(wsm[t], kT[h][t], acc);
        part[tid] = acc;
    }
    __syncthreads();
    if (tid < 64) {
        out[bn * H_ + tid] = part[tid] + part[64 + tid] + part[128 + tid] + part[192 + tid];
    }
}

extern "C" void kernel_launch(void* const* d_in, const int* in_sizes, int n_in,
                              void* d_out, int out_size, void* d_ws, size_t ws_size,
                              hipStream_t stream) {
    const float* queries = (const float*)d_in[0];
    const float* keys    = (const float*)d_in[1];
    const int*   klen    = (const int*)  d_in[2];
    const float* W1 = (const float*)d_in[3];
    const float* b1 = (const float*)d_in[4];
    const float* W2 = (const float*)d_in[5];
    const float* b2 = (const float*)d_in[6];
    const float* W3 = (const float*)d_in[7];
    const float* b3 = (const float*)d_in[8];
    float* out = (float*)d_out;

    // ws layout (16B multiples):
    // QW   [2048*80 f32]   =   655,360 B
    // kbf0 [106496 x 16B]  = 1,703,936 B
    // kbf1 [106496 x 16B]  = 1,703,936 B
    // WBF  [20*64 x 16B]   =    20,480 B
    // W2F  [2304 u32]      =     9,216 B
    const size_t nkbf = (size_t)B_ * NTILE * 64;
    const size_t need = 655360 + 2 * 1703936 + 20480 + 9216;

    if (ws_size >= need) {
        char* base = (char*)d_ws;
        float*  QW   = (float*)base;
        bf16x8* kbf0 = (bf16x8*)(base + 655360);
        bf16x8* kbf1 = kbf0 + nkbf;
        bf16x8* WBF  = kbf1 + nkbf;
        unsigned* W2F = (unsigned*)((char*)WBF + 20480);

        prep<<<dim3(P_QW + P_WB + P_KB + P_W2), dim3(256), 0, stream>>>(
            queries, keys, W1, b1, W2, QW, (unsigned*)WBF, kbf0, kbf1, W2F);
        attn13<<<dim3(B_ * N_), dim3(832), 0, stream>>>(
            queries, keys, klen, QW, kbf0, kbf1, WBF, (const bf16x8*)W2F,
            b2, W3, b3, out);
    } else {
        attn_nows<<<dim3(B_ * N_), dim3(256), 0, stream>>>(
            queries, keys, klen, W1, b1, W2, b2, W3, b3, out);
    }
}

// Round 12
// 58.110 us; speedup vs baseline: 1.4261x; 1.4261x over previous
//
#include <hip/hip_runtime.h>
#include <hip/hip_bf16.h>
#include <math.h>

#define B_  128
#define N_  16
#define T_  200
#define H_  64
#define J1  80
#define J2  40
#define NTILE 13
#define ZSTR  208              // per-bn score stride (13*16)
#define NEGV -4294967295.0f   // -2^32 + 1

typedef __attribute__((ext_vector_type(8))) short bf16x8;
typedef __attribute__((ext_vector_type(4))) float f32x4;

__device__ __forceinline__ float sigmoidf_(float x) {
    return 1.0f / (1.0f + __expf(-x));
}
// branch-free RNE f32->bf16 (finite inputs only)
__device__ __forceinline__ short f2b(float x) {
    unsigned u = __float_as_uint(x);
    return (short)((u + 0x7FFF + ((u >> 16) & 1)) >> 16);
}
__device__ __forceinline__ unsigned pack2(float a, float b) {
    return (unsigned)(unsigned short)f2b(a) | ((unsigned)(unsigned short)f2b(b) << 16);
}
// HW packed convert: dst = {lo16: bf16(a), hi16: bf16(b)} — one VALU op
__device__ __forceinline__ unsigned cvtpk(float a, float b) {
    unsigned r;
    asm("v_cvt_pk_bf16_f32 %0, %1, %2" : "=v"(r) : "v"(a), "v"(b));
    return r;
}
// kq word: in-register bf16 extract (1 op each) + mul + cvt_pk = 5 VALU
__device__ __forceinline__ unsigned kqword(unsigned w, float ql, float qh) {
    float lo = __uint_as_float(w << 16) * ql;
    float hi = __uint_as_float(w & 0xffff0000u) * qh;
    return cvtpk(lo, hi);
}

// ---- prep: ONE dispatch, 5 ranges --------------------------------------
#define P_QW 160
#define P_WB 20
#define P_KB 416
#define P_W2 9
#define P_PB 1
__global__ void prep(const float* __restrict__ queries,
                     const float* __restrict__ keys,
                     const float* __restrict__ W1,
                     const float* __restrict__ b1,
                     const float* __restrict__ W2,
                     const float* __restrict__ b2,
                     const float* __restrict__ W3,
                     float* __restrict__ QW,
                     unsigned* __restrict__ WBFu,
                     bf16x8* __restrict__ kbf0, bf16x8* __restrict__ kbf1,
                     unsigned* __restrict__ W2F,
                     float* __restrict__ b2p, float* __restrict__ W3p) {
    const int blk = blockIdx.x, tid = threadIdx.x;
    if (blk < P_QW) {
        int idx = blk * 256 + tid;                 // (bn, j/4), exact
        int bn = idx / 20, j = (idx % 20) * 4;
        float4 acc = *(const float4*)(b1 + j);
        const float* qp = queries + bn * H_;
        for (int h = 0; h < H_; ++h) {
            float qh = qp[h];
            float4 wa = *(const float4*)(W1 + h * J1 + j);
            float4 wc = *(const float4*)(W1 + (128 + h) * J1 + j);
            acc.x = fmaf(qh, wa.x + wc.x, acc.x);
            acc.y = fmaf(qh, wa.y + wc.y, acc.y);
            acc.z = fmaf(qh, wa.z + wc.z, acc.z);
            acc.w = fmaf(qh, wa.w + wc.w, acc.w);
        }
        *(float4*)(QW + bn * J1 + j) = acc;
    } else if (blk < P_QW + P_WB) {
        // WBF frag fi = s*5+nt; lane l holds rows R = s*32+8*(l>>4)+2rp(+1),
        // col j = nt*16+(l&15). Rows 0..63 = W1d, 64..127 = W1b - W1c.
        int idx = (blk - P_QW) * 256 + tid;        // = fi*256 + l*4 + rp, exact
        int rp = idx & 3, l = (idx >> 2) & 63, fi = idx >> 8;
        int j  = (fi % 5) * 16 + (l & 15);
        int R  = (fi / 5) * 32 + 8 * (l >> 4) + 2 * rp;
        float a, b;
        if (R < 64) {
            a = W1[(192 + R) * J1 + j];
            b = W1[(193 + R) * J1 + j];
        } else {
            int r2 = R - 64;
            a = W1[(64 + r2) * J1 + j] - W1[(128 + r2) * J1 + j];
            b = W1[(65 + r2) * J1 + j] - W1[(129 + r2) * J1 + j];
        }
        WBFu[idx] = pack2(a, b);
    } else if (blk < P_QW + P_WB + P_KB) {
        int idx = (blk - P_QW - P_WB) * 256 + tid; // (b*13+mt)*64+l, exact
        int l  = idx & 63, bm = idx >> 6;
        int mt = bm % NTILE, b = bm / NTILE;
        int t  = mt * 16 + (l & 15); if (t > T_ - 1) t = T_ - 1;
        int rg = l >> 4;
        const float* kr = keys + ((size_t)(b * T_ + t)) * H_ + 8 * rg;
        float4 a0 = *(const float4*)(kr);
        float4 a1 = *(const float4*)(kr + 4);
        float4 a2 = *(const float4*)(kr + 32);
        float4 a3 = *(const float4*)(kr + 36);
        bf16x8 f0, f1;
        f0[0] = f2b(a0.x); f0[1] = f2b(a0.y); f0[2] = f2b(a0.z); f0[3] = f2b(a0.w);
        f0[4] = f2b(a1.x); f0[5] = f2b(a1.y); f0[6] = f2b(a1.z); f0[7] = f2b(a1.w);
        f1[0] = f2b(a2.x); f1[1] = f2b(a2.y); f1[2] = f2b(a2.z); f1[3] = f2b(a2.w);
        f1[4] = f2b(a3.x); f1[5] = f2b(a3.y); f1[6] = f2b(a3.z); f1[7] = f2b(a3.w);
        kbf0[idx] = f0; kbf1[idx] = f1;
    } else if (blk < P_QW + P_WB + P_KB + P_W2) {
        int idx = (blk - P_QW - P_WB - P_KB) * 256 + tid;
        if (idx < 9 * 64 * 4) {
            int rp = idx & 3;
            int l  = (idx >> 2) & 63;
            int f  = idx >> 8;
            int m  = (f / 3) * 16 + (l & 15);
            int k0 = (f % 3) * 32 + 8 * (l >> 4) + 2 * rp;
            float a = (k0     < J1 && m < J2) ? W2[k0 * J2 + m]       : 0.0f;
            float b = (k0 + 1 < J1 && m < J2) ? W2[(k0 + 1) * J2 + m] : 0.0f;
            W2F[idx] = pack2(a, b);
        }
    } else {
        if (tid < 48) {
            b2p[tid] = (tid < J2) ? b2[tid] : 0.0f;
            W3p[tid] = (tid < J2) ? W3[tid] : 0.0f;
        }
    }
}

// ---- scores: ONE WAVE per (bn, mt); SWAPPED MFMA operands ---------------
// Z1^T = WBF(a) @ K^T(b): lane owns t=cl with 4 CONSECUTIVE j per nt ->
// cvt_pk pairs + ds_write_b64 (was 4x scalar f2b + ds_write_b16).
// Z2^T = W2F(a) @ X1^T(b): lane owns its own t -> layer-3 reduce is 2 shfl.
__global__ __launch_bounds__(256) void score2(
        const float* __restrict__ queries,
        const float* __restrict__ QW,
        const bf16x8* __restrict__ kbf0, const bf16x8* __restrict__ kbf1,
        const bf16x8* __restrict__ WBF, const bf16x8* __restrict__ W2F,
        const float* __restrict__ b2p, const float* __restrict__ W3p,
        const float* __restrict__ b3,
        float* __restrict__ z3ws) {
    const int tid  = threadIdx.x;
    const int lane = tid & 63, wv = tid >> 6;
    // bijective XCD swizzle: 6656 = 8*832
    const int bid  = (blockIdx.x & 7) * 832 + (blockIdx.x >> 3);
    const int job  = bid * 4 + wv;
    const int bn   = job / NTILE, mt = job % NTILE;
    const int b    = bn >> 4;
    const int cl   = lane & 15, rg = lane >> 4;

    __shared__ __align__(16) short X1[4][16][108];   // stride 108: 16 banks spread

    // zero k-pad cols 80..95 of own-wave slice
    #pragma unroll
    for (int i = 0; i < 4; ++i)
        X1[wv][rg + 4 * i][80 + cl] = 0;

    // b-operands: K frags (precomputed) and Kq = K*q (word ops + cvt_pk)
    bf16x8 k0 = kbf0[(b * NTILE + mt) * 64 + lane];
    bf16x8 k1 = kbf1[(b * NTILE + mt) * 64 + lane];
    const float* qp = queries + bn * H_;
    float4 qa = *(const float4*)(qp + 8 * rg);
    float4 qb = *(const float4*)(qp + 8 * rg + 4);
    float4 qc = *(const float4*)(qp + 32 + 8 * rg);
    float4 qd = *(const float4*)(qp + 36 + 8 * rg);
    const uint4 kw0 = *(const uint4*)&k0;
    const uint4 kw1 = *(const uint4*)&k1;
    uint4 kqw0, kqw1;
    kqw0.x = kqword(kw0.x, qa.x, qa.y);
    kqw0.y = kqword(kw0.y, qa.z, qa.w);
    kqw0.z = kqword(kw0.z, qb.x, qb.y);
    kqw0.w = kqword(kw0.w, qb.z, qb.w);
    kqw1.x = kqword(kw1.x, qc.x, qc.y);
    kqw1.y = kqword(kw1.y, qc.z, qc.w);
    kqw1.z = kqword(kw1.z, qd.x, qd.y);
    kqw1.w = kqword(kw1.w, qd.z, qd.w);
    bf16x8 kq0 = *(bf16x8*)&kqw0;
    bf16x8 kq1 = *(bf16x8*)&kqw1;

    // layer 1 (swapped): acc[nt] holds Z1^T rows j=16nt+4rg+i, col t=cl.
    // init = QW[j] (float4 broadcast within each 16-lane group)
    f32x4 acc[5];
    #pragma unroll
    for (int nt = 0; nt < 5; ++nt) {
        float4 qw4 = *(const float4*)(QW + bn * J1 + 16 * nt + 4 * rg);
        acc[nt][0] = qw4.x; acc[nt][1] = qw4.y; acc[nt][2] = qw4.z; acc[nt][3] = qw4.w;
    }
    #pragma unroll
    for (int nt = 0; nt < 5; ++nt) {
        acc[nt] = __builtin_amdgcn_mfma_f32_16x16x32_bf16(WBF[( 0 + nt) * 64 + lane], kq0, acc[nt], 0, 0, 0);
        acc[nt] = __builtin_amdgcn_mfma_f32_16x16x32_bf16(WBF[( 5 + nt) * 64 + lane], kq1, acc[nt], 0, 0, 0);
        acc[nt] = __builtin_amdgcn_mfma_f32_16x16x32_bf16(WBF[(10 + nt) * 64 + lane], k0,  acc[nt], 0, 0, 0);
        acc[nt] = __builtin_amdgcn_mfma_f32_16x16x32_bf16(WBF[(15 + nt) * 64 + lane], k1,  acc[nt], 0, 0, 0);
    }

    // sigmoid -> X1[t=cl][j], 4 consecutive j per nt: 2 cvt_pk + 1 b64 write
    #pragma unroll
    for (int nt = 0; nt < 5; ++nt) {
        unsigned r0 = cvtpk(sigmoidf_(acc[nt][0]), sigmoidf_(acc[nt][1]));
        unsigned r1 = cvtpk(sigmoidf_(acc[nt][2]), sigmoidf_(acc[nt][3]));
        *(uint2*)&X1[wv][cl][16 * nt + 4 * rg] = make_uint2(r0, r1);
    }

    // layer 2 (swapped): acc2[nt] holds Z2^T rows m=16nt+4rg+i, col t=cl
    f32x4 acc2[3];
    #pragma unroll
    for (int nt = 0; nt < 3; ++nt) {
        float4 bb = *(const float4*)(b2p + 16 * nt + 4 * rg);
        acc2[nt][0] = bb.x; acc2[nt][1] = bb.y; acc2[nt][2] = bb.z; acc2[nt][3] = bb.w;
    }
    #pragma unroll
    for (int ks = 0; ks < 3; ++ks) {
        bf16x8 xa = *(const bf16x8*)&X1[wv][cl][8 * rg + 32 * ks];  // own row
        acc2[0] = __builtin_amdgcn_mfma_f32_16x16x32_bf16(W2F[(0 + ks) * 64 + lane], xa, acc2[0], 0, 0, 0);
        acc2[1] = __builtin_amdgcn_mfma_f32_16x16x32_bf16(W2F[(3 + ks) * 64 + lane], xa, acc2[1], 0, 0, 0);
        acc2[2] = __builtin_amdgcn_mfma_f32_16x16x32_bf16(W2F[(6 + ks) * 64 + lane], xa, acc2[2], 0, 0, 0);
    }

    // layer 3: lane owns t=cl; p = sum over its 12 m's, then 2 shfl (rg dim)
    float p = 0.f;
    #pragma unroll
    for (int nt = 0; nt < 3; ++nt) {
        float4 w34 = *(const float4*)(W3p + 16 * nt + 4 * rg);   // 0 for m>=40
        p = fmaf(sigmoidf_(acc2[nt][0]), w34.x, p);
        p = fmaf(sigmoidf_(acc2[nt][1]), w34.y, p);
        p = fmaf(sigmoidf_(acc2[nt][2]), w34.z, p);
        p = fmaf(sigmoidf_(acc2[nt][3]), w34.w, p);
    }
    p += __shfl_xor(p, 16);
    p += __shfl_xor(p, 32);
    if (rg == 0)
        z3ws[(size_t)bn * ZSTR + mt * 16 + cl] = p + b3[0];
}

// ---- softmax + weighted sum: block per bn (verified R10 code) ------------
__global__ __launch_bounds__(256) void softmax_pv(
        const float* __restrict__ keys, const int* __restrict__ keys_length,
        const float* __restrict__ z3ws, float* __restrict__ out) {
    const int tid = threadIdx.x;
    const int bn  = (blockIdx.x & 7) * 256 + (blockIdx.x >> 3);  // XCD swizzle
    const int b   = bn >> 4;

    __shared__ float wsm[T_];
    __shared__ float part[256];
    __shared__ float red[8];

    const int L = keys_length[b];
    float s = (tid < T_) ? ((tid < L) ? z3ws[(size_t)bn * ZSTR + tid] : NEGV) * 0.125f
                         : -3.0e38f;

    float mx = s;
    #pragma unroll
    for (int off = 32; off > 0; off >>= 1) mx = fmaxf(mx, __shfl_xor(mx, off));
    if ((tid & 63) == 0) red[tid >> 6] = mx;
    __syncthreads();
    mx = fmaxf(fmaxf(red[0], red[1]), fmaxf(red[2], red[3]));

    float e = (tid < T_) ? __expf(s - mx) : 0.0f;
    float sm = e;
    #pragma unroll
    for (int off = 32; off > 0; off >>= 1) sm += __shfl_xor(sm, off);
    __syncthreads();
    if ((tid & 63) == 0) red[4 + (tid >> 6)] = sm;
    __syncthreads();
    sm = red[4] + red[5] + red[6] + red[7];

    if (tid < T_) wsm[tid] = e / sm;
    __syncthreads();

    const float* kb = keys + (size_t)b * T_ * H_;
    {
        int h = tid & 63, p = tid >> 6;
        float acc = 0.f;
        int tb = p * 50;
        #pragma unroll 5
        for (int t = tb; t < tb + 50; ++t)
            acc = fmaf(wsm[t], kb[(size_t)t * H_ + h], acc);
        part[tid] = acc;
    }
    __syncthreads();
    if (tid < 64) {
        out[bn * H_ + tid] = part[tid] + part[64 + tid] + part[128 + tid] + part[192 + tid];
    }
}

// --- fallback (no workspace): round-3 verified pure-VALU kernel ----------
__global__ __launch_bounds__(256, 3) void attn_nows(
        const float* __restrict__ queries, const float* __restrict__ keys,
        const int*   __restrict__ keys_length,
        const float* __restrict__ W1, const float* __restrict__ b1,
        const float* __restrict__ W2, const float* __restrict__ b2,
        const float* __restrict__ W3, const float* __restrict__ b3,
        float* __restrict__ out) {
    const int tid = threadIdx.x;
    const int bn = (blockIdx.x & 7) * 256 + (blockIdx.x >> 3);
    const int b  = bn >> 4;

    __shared__ float kT[H_][T_ + 1];
    __shared__ float wsm[T_];
    __shared__ float part[256];
    __shared__ float red[8];
    __shared__ float QWq[J1];

    for (int idx = tid; idx < T_ * H_; idx += 256) {
        int t = idx >> 6, h = idx & 63;
        kT[h][t] = keys[(b * T_ + t) * H_ + h];
    }
    if (tid < J1) {
        float acc = b1[tid];
        const float* qp = queries + bn * H_;
        for (int h = 0; h < H_; ++h)
            acc = fmaf(qp[h], W1[h * J1 + tid] + W1[(128 + h) * J1 + tid], acc);
        QWq[tid] = acc;
    }
    __syncthreads();

    const int tt = (tid < T_) ? tid : 0;
    const float* qp = queries + bn * H_;

    float qk[H_];
    #pragma unroll
    for (int h = 0; h < H_; ++h) qk[h] = qp[h] * kT[h][tt];

    float z2[J2];
    #pragma unroll
    for (int m = 0; m < J2; ++m) z2[m] = b2[m];

    #pragma unroll 1
    for (int c = 0; c < 4; ++c) {
        const int j0 = c * 20;
        float z1c[20];
        #pragma unroll
        for (int j = 0; j < 20; ++j) z1c[j] = QWq[j0 + j];
        #pragma unroll
        for (int h = 0; h < H_; ++h) {
            float kh = kT[h][tt];
            const float* Wd = W1 + (192 + h) * J1 + j0;
            const float* Wb = W1 + (64 + h) * J1 + j0;
            const float* Wc = W1 + (128 + h) * J1 + j0;
            #pragma unroll
            for (int j = 0; j < 20; ++j)
                z1c[j] = fmaf(qk[h], Wd[j], fmaf(kh, Wb[j] - Wc[j], z1c[j]));
        }
        #pragma unroll
        for (int j = 0; j < 20; ++j) {
            float x = sigmoidf_(z1c[j]);
            const float* w2 = W2 + (j0 + j) * J2;
            #pragma unroll
            for (int m = 0; m < J2; ++m) z2[m] = fmaf(x, w2[m], z2[m]);
        }
    }

    float z3 = b3[0];
    #pragma unroll
    for (int m = 0; m < J2; ++m) z3 = fmaf(sigmoidf_(z2[m]), W3[m], z3);

    const int L = keys_length[b];
    float s = (tid < T_) ? ((tid < L) ? z3 : NEGV) * 0.125f : -3.0e38f;

    float mx = s;
    #pragma unroll
    for (int off = 32; off > 0; off >>= 1) mx = fmaxf(mx, __shfl_xor(mx, off));
    if ((tid & 63) == 0) red[tid >> 6] = mx;
    __syncthreads();
    mx = fmaxf(fmaxf(red[0], red[1]), fmaxf(red[2], red[3]));

    float e = (tid < T_) ? __expf(s - mx) : 0.0f;
    float sm = e;
    #pragma unroll
    for (int off = 32; off > 0; off >>= 1) sm += __shfl_xor(sm, off);
    __syncthreads();
    if ((tid & 63) == 0) red[4 + (tid >> 6)] = sm;
    __syncthreads();
    sm = red[4] + red[5] + red[6] + red[7];

    if (tid < T_) wsm[tid] = e / sm;
    __syncthreads();

    {
        int h = tid & 63, p = tid >> 6;
        float acc = 0.f;
        int t0 = p * 50;
        for (int t = t0; t < t0 + 50; ++t)
            acc = fmaf(wsm[t], kT[h][t], acc);
        part[tid] = acc;
    }
    __syncthreads();
    if (tid < 64) {
        out[bn * H_ + tid] = part[tid] + part[64 + tid] + part[128 + tid] + part[192 + tid];
    }
}

extern "C" void kernel_launch(void* const* d_in, const int* in_sizes, int n_in,
                              void* d_out, int out_size, void* d_ws, size_t ws_size,
                              hipStream_t stream) {
    const float* queries = (const float*)d_in[0];
    const float* keys    = (const float*)d_in[1];
    const int*   klen    = (const int*)  d_in[2];
    const float* W1 = (const float*)d_in[3];
    const float* b1 = (const float*)d_in[4];
    const float* W2 = (const float*)d_in[5];
    const float* b2 = (const float*)d_in[6];
    const float* W3 = (const float*)d_in[7];
    const float* b3 = (const float*)d_in[8];
    float* out = (float*)d_out;

    // ws layout (16B multiples):
    // QW   [2048*80 f32]   =   655,360 B
    // kbf0 [106496 x 16B]  = 1,703,936 B
    // kbf1 [106496 x 16B]  = 1,703,936 B
    // WBF  [20*64 x 16B]   =    20,480 B
    // W2F  [2304 u32]      =     9,216 B
    // b2p/W3p [48 f32 each]=       512 B
    // z3   [2048*208 f32]  = 1,703,936 B
    const size_t nkbf = (size_t)B_ * NTILE * 64;
    const size_t need = 655360 + 2 * 1703936 + 20480 + 9216 + 512 + 1703936;

    if (ws_size >= need) {
        char* base = (char*)d_ws;
        float*  QW   = (float*)base;
        bf16x8* kbf0 = (bf16x8*)(base + 655360);
        bf16x8* kbf1 = kbf0 + nkbf;
        bf16x8* WBF  = kbf1 + nkbf;
        unsigned* W2F = (unsigned*)((char*)WBF + 20480);
        float*  b2p  = (float*)((char*)W2F + 9216);
        float*  W3p  = b2p + 64;
        float*  z3ws = (float*)((char*)W2F + 9216 + 512);

        prep<<<dim3(P_QW + P_WB + P_KB + P_W2 + P_PB), dim3(256), 0, stream>>>(
            queries, keys, W1, b1, W2, b2, W3,
            QW, (unsigned*)WBF, kbf0, kbf1, W2F, b2p, W3p);
        score2<<<dim3(6656), dim3(256), 0, stream>>>(
            queries, QW, kbf0, kbf1, WBF, (const bf16x8*)W2F, b2p, W3p, b3, z3ws);
        softmax_pv<<<dim3(B_ * N_), dim3(256), 0, stream>>>(keys, klen, z3ws, out);
    } else {
        attn_nows<<<dim3(B_ * N_), dim3(256), 0, stream>>>(
            queries, keys, klen, W1, b1, W2, b2, W3, b3, out);
    }
}